// Round 6
// baseline (1999.045 us; speedup 1.0000x reference)
//
#include <hip/hip_runtime.h>

typedef unsigned int uint;
typedef unsigned long long u64;
typedef _Float16 f16;
typedef _Float16 f16x2 __attribute__((ext_vector_type(2)));
typedef _Float16 f16x8 __attribute__((ext_vector_type(8)));
typedef float f32x4 __attribute__((ext_vector_type(4)));

#define N_TYPES 10000
#define HID 256
#define G4 1024
#define BATCH 32
#define SEQ 1024

// ---------------- K1: path table: path[n][h] = sum_d cumw_d * emb[anc[n,d]][h]
__global__ void k_path(const int* __restrict__ anc, const float* __restrict__ weight,
                       const float* __restrict__ emb, int D, f16* __restrict__ path) {
  int n = blockIdx.x;
  int h = threadIdx.x;
  float acc = 0.f, cw = 1.f;
  for (int d = 0; d < D; ++d) {
    int a = anc[n * D + d];
    if (a < 0) break;
    acc += cw * emb[a * HID + h];
    cw *= weight[a];
  }
  path[n * HID + h] = (f16)acc;
}

// ---------------- K0: convert W_ih -> f16, W_hh -> transposed packed f16 pairs, bias = b_ih+b_hh
// whh_t layout: [128 kpair][1024 row] u32 (pair = f16 k, k+1 of row)
__global__ void k_conv(const float* __restrict__ wih, const float* __restrict__ whh,
                       const float* __restrict__ bih, const float* __restrict__ bhh,
                       f16* __restrict__ wih_h, uint* __restrict__ whh_t,
                       float* __restrict__ bias) {
  int i = blockIdx.x * 256 + threadIdx.x;   // 262144 threads
  wih_h[i] = (f16)wih[i];
  if (i < G4 * 128) {
    int row = i >> 7, p = i & 127;
    f16x2 v;
    v.x = (f16)whh[row * HID + 2 * p];
    v.y = (f16)whh[row * HID + 2 * p + 1];
    whh_t[p * G4 + row] = __builtin_bit_cast(uint, v);
  }
  if (i < G4) bias[i] = bih[i] + bhh[i];
}

// ---------------- K2: proj[n][r] = sum_k path[n][k]*W_ih[r][k] + bias[r]   (M=10000,N=1024,K=256)
#define BM 128
#define BN 128
#define BK 64
#define LPAD 72
__global__ __launch_bounds__(256) void k_gemm(const f16* __restrict__ A,
                                              const f16* __restrict__ Bw,
                                              const float* __restrict__ bias,
                                              f16* __restrict__ C) {
  __shared__ f16 sA[BM][LPAD];
  __shared__ f16 sB[BN][LPAD];
  int m0 = blockIdx.x * BM, n0 = blockIdx.y * BN;
  int tid = threadIdx.x;
  int wid = tid >> 6, lane = tid & 63;
  int wm = wid & 1, wn = wid >> 1;
  f32x4 acc[4][4] = {};
  for (int k0 = 0; k0 < 256; k0 += BK) {
    __syncthreads();
    int r = tid >> 3, kc = (tid & 7) * 8;
    for (int i = 0; i < 4; ++i) {
      int row = r + 32 * i;
      int gm = m0 + row;
      uint4 va = make_uint4(0u, 0u, 0u, 0u);
      if (gm < N_TYPES) va = *(const uint4*)&A[gm * 256 + k0 + kc];
      *(uint4*)&sA[row][kc] = va;
      uint4 vb = *(const uint4*)&Bw[(n0 + row) * 256 + k0 + kc];
      *(uint4*)&sB[row][kc] = vb;
    }
    __syncthreads();
#pragma unroll
    for (int ks = 0; ks < 2; ++ks) {
      f16x8 af[4], bf[4];
      int kk = ks * 32 + (lane >> 4) * 8;
#pragma unroll
      for (int mt = 0; mt < 4; ++mt)
        af[mt] = *(const f16x8*)&sA[wm * 64 + mt * 16 + (lane & 15)][kk];
#pragma unroll
      for (int nt = 0; nt < 4; ++nt)
        bf[nt] = *(const f16x8*)&sB[wn * 64 + nt * 16 + (lane & 15)][kk];
#pragma unroll
      for (int mt = 0; mt < 4; ++mt)
#pragma unroll
        for (int nt = 0; nt < 4; ++nt)
          acc[mt][nt] = __builtin_amdgcn_mfma_f32_16x16x32_f16(af[mt], bf[nt], acc[mt][nt], 0, 0, 0);
    }
  }
#pragma unroll
  for (int mt = 0; mt < 4; ++mt)
#pragma unroll
    for (int nt = 0; nt < 4; ++nt)
#pragma unroll
      for (int qq = 0; qq < 4; ++qq) {
        int row = m0 + wm * 64 + mt * 16 + (lane >> 4) * 4 + qq;
        int col = n0 + wn * 64 + nt * 16 + (lane & 15);
        if (row < N_TYPES) C[row * G4 + col] = (f16)(acc[mt][nt][qq] + bias[col]);
      }
}

// ---------------- K3: LSTM recurrence, v5.
// Same proven R5 skeleton: 256 WGs of 512 thr, bid=q*32+b; WG q owns dims
// [q*32,q*32+32) for 4 gates = 128 rows; row k-split over 4 waves (kq = wave>>1).
// Sync: self-validating {f16x2, step-tag} u64 words, RELAXED agent atomics
// (served by XCD-local L2 per R5 FETCH evidence; no L2 invalidation ever).
//
// R5 post-mortem fixes:
//  (a) T14 weight prefetch: the RA never keeps weights resident (28 VGPRs in R5!)
//      and sinks the demoted reloads AFTER the poll -> ~500-800cy serialized L2
//      stream on the critical path. Fix: issue all 32 weight loads at step top
//      (opaque z index defeats LICM/remat; sched_barrier(0) pins issue order),
//      so they stream during the poll window.
//  (b) single barrier: t<32 sums its 16 partials directly from parity-double-
//      buffered pl[2][512] and applies activations -- removes barrier[2] and the
//      128-thread rt stage.
__device__ __forceinline__ float dot2(uint wp, uint hp, float acc) {
#if __has_builtin(__builtin_amdgcn_fdot2)
  return __builtin_amdgcn_fdot2(__builtin_bit_cast(f16x2, wp),
                                __builtin_bit_cast(f16x2, hp), acc, false);
#else
  f16x2 a = __builtin_bit_cast(f16x2, wp);
  f16x2 b = __builtin_bit_cast(f16x2, hp);
  return acc + (float)a.x * (float)b.x + (float)a.y * (float)b.y;
#endif
}

__device__ __forceinline__ float sigm(float v) { return 1.f / (1.f + __expf(-v)); }
__device__ __forceinline__ float tanh_(float v) { return 1.f - 2.f / (__expf(2.f * v) + 1.f); }

__global__ __launch_bounds__(512)
void k_lstm(const int* __restrict__ evs,
            const f16* __restrict__ proj,
            const uint* __restrict__ whh_t,
            u64* hglob,                 // [32 batch][2 slot][128 pair] tagged words
            float* __restrict__ out) {
  int bid = blockIdx.x;
  int b = bid & 31, q = bid >> 5;      // 8 WGs of batch b share bid%8 -> same XCD
  int t = threadIdx.x;
  int v = t >> 6, l = t & 63;
  int kq = v >> 1;                     // k-quarter, wave-uniform
  int rid = (v & 1) * 64 + l;          // local gate-row 0..127 (= g*32 + jj)
  int rowg = (rid >> 5) * 256 + q * 32 + (rid & 31);

  __shared__ float pl[2][512];

  u64* hb = hglob + b * 256;
  const int* ev = evs + b * SEQ;
  const uint* wbase = whh_t + (kq * 32) * G4 + rowg;

  // t<32: x prefetch state = proj[e][g*256 + q*32 + t] for 4 gates
  float x4[4] = {0.f, 0.f, 0.f, 0.f};
  if (t < 32) {
    int e0 = ev[0];
#pragma unroll
    for (int g = 0; g < 4; ++g)
      x4[g] = (float)proj[(long)e0 * G4 + g * 256 + q * 32 + t];
  }

  float c = 0.f;

  for (int step = 0; step < SEQ; ++step) {
    // (1) issue weight loads NOW; opaque z prevents hoist-out + per-use remat
    uint z = 0;
    asm volatile("" : "+v"(z));
    uint wl[32];
#pragma unroll
    for (int i = 0; i < 32; ++i) wl[i] = wbase[i * G4 + z];
    __builtin_amdgcn_sched_barrier(0);   // keep loads issued before the poll

    // (2) poll h_{step-1} (lanes 0..31 of each wave = readlane sources)
    int h0 = 0;
    if (step > 0) {
      if (l < 32) {
        const u64* src = hb + ((step - 1) & 1) * 128 + kq * 32 + l;
        u64 val;
        do {
          val = __hip_atomic_load(src, __ATOMIC_RELAXED, __HIP_MEMORY_SCOPE_AGENT);
        } while ((uint)(val >> 32) != (uint)step);
        h0 = (int)(uint)val;
      }
    }

    // (3) partial dot over pairs [kq*32, kq*32+32)  (weights already in flight)
    float a0 = 0.f, a1 = 0.f, a2 = 0.f, a3 = 0.f;
#pragma unroll
    for (int i = 0; i < 32; i += 4) {
      a0 = dot2(wl[i + 0], (uint)__builtin_amdgcn_readlane(h0, i + 0), a0);
      a1 = dot2(wl[i + 1], (uint)__builtin_amdgcn_readlane(h0, i + 1), a1);
      a2 = dot2(wl[i + 2], (uint)__builtin_amdgcn_readlane(h0, i + 2), a2);
      a3 = dot2(wl[i + 3], (uint)__builtin_amdgcn_readlane(h0, i + 3), a3);
    }
    pl[step & 1][kq * 128 + rid] = (a0 + a1) + (a2 + a3);

    // (4) prefetch next step's x (off critical chain; consumed next step)
    float x4n[4] = {0.f, 0.f, 0.f, 0.f};
    if (t < 32 && step + 1 < SEQ) {
      int e2 = ev[step + 1];
#pragma unroll
      for (int g = 0; g < 4; ++g)
        x4n[g] = (float)proj[(long)e2 * G4 + g * 256 + q * 32 + t];
    }

    __syncthreads();                     // the ONLY barrier per step

    // (5) reduce(16 LDS reads) + activations + publish, all on t<32
    if (t < 32) {
      const float* pp = pl[step & 1];
      float s0 = pp[t]        + pp[128 + t]        + pp[256 + t]        + pp[384 + t]        + x4[0];
      float s1 = pp[32 + t]   + pp[128 + 32 + t]   + pp[256 + 32 + t]   + pp[384 + 32 + t]   + x4[1];
      float s2 = pp[64 + t]   + pp[128 + 64 + t]   + pp[256 + 64 + t]   + pp[384 + 64 + t]   + x4[2];
      float s3 = pp[96 + t]   + pp[128 + 96 + t]   + pp[256 + 96 + t]   + pp[384 + 96 + t]   + x4[3];
      float iv = sigm(s0), fv = sigm(s1), gv = tanh_(s2), ov = sigm(s3);
      c = fv * c + iv * gv;
      float hval = ov * tanh_(c);
      out[(step * BATCH + b) * HID + q * 32 + t] = hval;
      float hA = __shfl(hval, 2 * (t & 15));
      float hB = __shfl(hval, 2 * (t & 15) + 1);
      if (t < 16) {
        f16x2 pk; pk.x = (f16)hA; pk.y = (f16)hB;
        u64 val = (u64)__builtin_bit_cast(uint, pk) | ((u64)(uint)(step + 1) << 32);
        __hip_atomic_store(hb + (step & 1) * 128 + q * 16 + t, val,
                           __ATOMIC_RELAXED, __HIP_MEMORY_SCOPE_AGENT);
      }
    }
#pragma unroll
    for (int g = 0; g < 4; ++g) x4[g] = x4n[g];
    // pl hazard note: step s reads pl[s&1] happen before t<32 reaches barrier(s+1);
    // any thread writes pl[s&1] again only after barrier(s+1). Safe with 1 barrier.
  }
}

extern "C" void kernel_launch(void* const* d_in, const int* in_sizes, int n_in,
                              void* d_out, int out_size, void* d_ws, size_t ws_size,
                              hipStream_t stream) {
  (void)n_in; (void)out_size; (void)ws_size;
  const int* evs = (const int*)d_in[0];
  const int* anc = (const int*)d_in[1];
  const float* weight = (const float*)d_in[2];
  const float* emb = (const float*)d_in[3];
  const float* wih = (const float*)d_in[4];
  const float* whh = (const float*)d_in[5];
  const float* bih = (const float*)d_in[6];
  const float* bhh = (const float*)d_in[7];
  int D = in_sizes[1] / N_TYPES;

  char* ws = (char*)d_ws;
  f16* path = (f16*)(ws);                       // 10000*256*2 = 5,120,000 (dead after k_gemm)
  f16* wih_h = (f16*)(ws + 5242880);            // 524,288
  uint* whh_t = (uint*)(ws + 5767168);          // 524,288
  float* bias = (float*)(ws + 6291456);         // 4,096
  f16* proj = (f16*)(ws + 6295552);             // 10000*1024*2 = 20,480,000
  u64* hglob = (u64*)(ws + 26775552);           // 32*2*128*8 = 65,536
  float* out = (float*)d_out;

  k_conv<<<1024, 256, 0, stream>>>(wih, whh, bih, bhh, wih_h, whh_t, bias);
  k_path<<<N_TYPES, 256, 0, stream>>>(anc, weight, emb, D, path);
  k_gemm<<<dim3(79, 8), 256, 0, stream>>>(path, wih_h, bias, proj);
  hipMemsetAsync(hglob, 0, 32 * 2 * 128 * 8, stream);   // zero tags (replay-safe)
  k_lstm<<<256, 512, 0, stream>>>(evs, proj, whh_t, hglob, out);
}

// Round 7
// 1814.584 us; speedup vs baseline: 1.1017x; 1.1017x over previous
//
#include <hip/hip_runtime.h>

typedef unsigned int uint;
typedef unsigned long long u64;
typedef unsigned short ushort;
typedef _Float16 f16;
typedef _Float16 f16x2 __attribute__((ext_vector_type(2)));
typedef _Float16 f16x8 __attribute__((ext_vector_type(8)));
typedef float f32x4 __attribute__((ext_vector_type(4)));

#define N_TYPES 10000
#define HID 256
#define G4 1024
#define BATCH 32
#define SEQ 1024

// ---------------- K1: path table: path[n][h] = sum_d cumw_d * emb[anc[n,d]][h]
__global__ void k_path(const int* __restrict__ anc, const float* __restrict__ weight,
                       const float* __restrict__ emb, int D, f16* __restrict__ path) {
  int n = blockIdx.x;
  int h = threadIdx.x;
  float acc = 0.f, cw = 1.f;
  for (int d = 0; d < D; ++d) {
    int a = anc[n * D + d];
    if (a < 0) break;
    acc += cw * emb[a * HID + h];
    cw *= weight[a];
  }
  path[n * HID + h] = (f16)acc;
}

// ---------------- K0: convert W_ih -> f16, W_hh -> transposed packed f16 pairs, bias = b_ih+b_hh
// whh_t layout: [128 kpair][1024 row] u32 (pair = f16 k, k+1 of row)
__global__ void k_conv(const float* __restrict__ wih, const float* __restrict__ whh,
                       const float* __restrict__ bih, const float* __restrict__ bhh,
                       f16* __restrict__ wih_h, uint* __restrict__ whh_t,
                       float* __restrict__ bias) {
  int i = blockIdx.x * 256 + threadIdx.x;   // 262144 threads
  wih_h[i] = (f16)wih[i];
  if (i < G4 * 128) {
    int row = i >> 7, p = i & 127;
    f16x2 v;
    v.x = (f16)whh[row * HID + 2 * p];
    v.y = (f16)whh[row * HID + 2 * p + 1];
    whh_t[p * G4 + row] = __builtin_bit_cast(uint, v);
  }
  if (i < G4) bias[i] = bih[i] + bhh[i];
}

// ---------------- K2: proj[n][dim][gate] = path[n]@W_ih^T + b (gate-packed epilogue)
// Output layout change vs R6: element (row=n, col=g*256+dim) stored at n*1024 + dim*4 + g
// so the LSTM's per-dim x-gather is ONE 8B load (4 f16) instead of 4 scattered 2B loads.
#define BM 128
#define BN 128
#define BK 64
#define LPAD 72
__global__ __launch_bounds__(256) void k_gemm(const f16* __restrict__ A,
                                              const f16* __restrict__ Bw,
                                              const float* __restrict__ bias,
                                              f16* __restrict__ C) {
  __shared__ f16 sA[BM][LPAD];
  __shared__ f16 sB[BN][LPAD];
  int m0 = blockIdx.x * BM, n0 = blockIdx.y * BN;
  int tid = threadIdx.x;
  int wid = tid >> 6, lane = tid & 63;
  int wm = wid & 1, wn = wid >> 1;
  f32x4 acc[4][4] = {};
  for (int k0 = 0; k0 < 256; k0 += BK) {
    __syncthreads();
    int r = tid >> 3, kc = (tid & 7) * 8;
    for (int i = 0; i < 4; ++i) {
      int row = r + 32 * i;
      int gm = m0 + row;
      uint4 va = make_uint4(0u, 0u, 0u, 0u);
      if (gm < N_TYPES) va = *(const uint4*)&A[gm * 256 + k0 + kc];
      *(uint4*)&sA[row][kc] = va;
      uint4 vb = *(const uint4*)&Bw[(n0 + row) * 256 + k0 + kc];
      *(uint4*)&sB[row][kc] = vb;
    }
    __syncthreads();
#pragma unroll
    for (int ks = 0; ks < 2; ++ks) {
      f16x8 af[4], bf[4];
      int kk = ks * 32 + (lane >> 4) * 8;
#pragma unroll
      for (int mt = 0; mt < 4; ++mt)
        af[mt] = *(const f16x8*)&sA[wm * 64 + mt * 16 + (lane & 15)][kk];
#pragma unroll
      for (int nt = 0; nt < 4; ++nt)
        bf[nt] = *(const f16x8*)&sB[wn * 64 + nt * 16 + (lane & 15)][kk];
#pragma unroll
      for (int mt = 0; mt < 4; ++mt)
#pragma unroll
        for (int nt = 0; nt < 4; ++nt)
          acc[mt][nt] = __builtin_amdgcn_mfma_f32_16x16x32_f16(af[mt], bf[nt], acc[mt][nt], 0, 0, 0);
    }
  }
#pragma unroll
  for (int mt = 0; mt < 4; ++mt)
#pragma unroll
    for (int nt = 0; nt < 4; ++nt)
#pragma unroll
      for (int qq = 0; qq < 4; ++qq) {
        int row = m0 + wm * 64 + mt * 16 + (lane >> 4) * 4 + qq;
        int col = n0 + wn * 64 + nt * 16 + (lane & 15);
        int dim = col & 255, g = col >> 8;
        if (row < N_TYPES)
          C[row * G4 + dim * 4 + g] = (f16)(acc[mt][nt][qq] + bias[col]);
      }
}

// ---------------- K3: LSTM recurrence, v6: W_hh in LDS.
// Skeleton as R5/R6 (proven): 256 WGs of 512 thr, bid=q*32+b; WG q owns dims
// [q*32,q*32+32) for 4 gates = 128 rows; row k-split over 4 waves (kq = wave>>1).
// Sync: self-validating {f16x2, step-tag} u64 relaxed agent atomics (R5; L2-served,
// never invalidates L2).
//
// R6 post-mortem: ANY scheme keeping a weights array in VGPRs across the step loop
// fails -- RA spills it (R6: VGPR=36 => 32 in-flight loads went to scratch) and the
// poll's vmcnt(0) drains prefetch loads anyway. Fix: weights live in LDS.
//  * 64 KiB/WG: [8 group][512 thr] uint4; per-step 8x ds_read_b128, 16B/lane
//    contiguous = conflict-free; lgkmcnt does NOT interact with the poll's vmcnt(0).
//  * x-gather is one 8B load (gate-packed proj layout).
__device__ __forceinline__ float dot2(uint wp, uint hp, float acc) {
#if __has_builtin(__builtin_amdgcn_fdot2)
  return __builtin_amdgcn_fdot2(__builtin_bit_cast(f16x2, wp),
                                __builtin_bit_cast(f16x2, hp), acc, false);
#else
  f16x2 a = __builtin_bit_cast(f16x2, wp);
  f16x2 b = __builtin_bit_cast(f16x2, hp);
  return acc + (float)a.x * (float)b.x + (float)a.y * (float)b.y;
#endif
}

__device__ __forceinline__ float sigm(float v) { return 1.f / (1.f + __expf(-v)); }
__device__ __forceinline__ float tanh_(float v) { return 1.f - 2.f / (__expf(2.f * v) + 1.f); }
__device__ __forceinline__ float f16u(ushort u) { return (float)__builtin_bit_cast(f16, u); }

__global__ __launch_bounds__(512)
void k_lstm(const int* __restrict__ evs,
            const f16* __restrict__ proj,
            const uint* __restrict__ whh_t,
            u64* hglob,                 // [32 batch][2 slot][128 pair] tagged words
            float* __restrict__ out) {
  int bid = blockIdx.x;
  int b = bid & 31, q = bid >> 5;      // 8 WGs of batch b share bid%8 -> same XCD
  int t = threadIdx.x;
  int v = t >> 6, l = t & 63;
  int kq = v >> 1;                     // k-quarter, wave-uniform
  int rid = (v & 1) * 64 + l;          // local gate-row 0..127 (= g*32 + jj)
  int rowg = (rid >> 5) * 256 + q * 32 + (rid & 31);

  __shared__ uint4 wlds[8 * 512];      // 64 KiB: group i4 -> pairs kq*32+4*i4..+3
  __shared__ float pl[2][128][4];      // partials [parity][rid][kq]

  // ---- stage W_hh slice into LDS (one-time; rows shared by all 32 b-WGs -> L2 hits)
  {
    const uint* wb = whh_t + (kq * 32) * G4 + rowg;
#pragma unroll
    for (int i4 = 0; i4 < 8; ++i4) {
      uint4 wv;
      wv.x = wb[(4 * i4 + 0) * G4];
      wv.y = wb[(4 * i4 + 1) * G4];
      wv.z = wb[(4 * i4 + 2) * G4];
      wv.w = wb[(4 * i4 + 3) * G4];
      wlds[i4 * 512 + t] = wv;
    }
  }
  __syncthreads();

  u64* hb = hglob + b * 256;
  const int* ev = evs + b * SEQ;

  // t<32 carries x for dim q*32+t, all 4 gates, one step ahead
  float x0 = 0.f, x1 = 0.f, x2 = 0.f, x3 = 0.f;
  if (t < 32) {
    ushort4 xv = *(const ushort4*)(proj + (long)ev[0] * G4 + (q * 32 + t) * 4);
    x0 = f16u(xv.x); x1 = f16u(xv.y); x2 = f16u(xv.z); x3 = f16u(xv.w);
  }

  float c = 0.f;

  for (int step = 0; step < SEQ; ++step) {
    // (1) poll h_{step-1} (lanes 0..31 = readlane sources; vmcnt-only, no lgkm)
    int h0 = 0;
    if (step > 0 && l < 32) {
      const u64* src = hb + ((step - 1) & 1) * 128 + kq * 32 + l;
      u64 val;
      do {
        val = __hip_atomic_load(src, __ATOMIC_RELAXED, __HIP_MEMORY_SCOPE_AGENT);
      } while ((uint)(val >> 32) != (uint)step);
      h0 = (int)(uint)val;
    }

    // (2) matvec partial over pairs [kq*32, kq*32+32): LDS weights + readlane h
    float a0 = 0.f, a1 = 0.f, a2 = 0.f, a3 = 0.f;
#pragma unroll
    for (int i4 = 0; i4 < 8; ++i4) {
      uint4 wv = wlds[i4 * 512 + t];
      a0 = dot2(wv.x, (uint)__builtin_amdgcn_readlane(h0, 4 * i4 + 0), a0);
      a1 = dot2(wv.y, (uint)__builtin_amdgcn_readlane(h0, 4 * i4 + 1), a1);
      a2 = dot2(wv.z, (uint)__builtin_amdgcn_readlane(h0, 4 * i4 + 2), a2);
      a3 = dot2(wv.w, (uint)__builtin_amdgcn_readlane(h0, 4 * i4 + 3), a3);
    }
    pl[step & 1][rid][kq] = (a0 + a1) + (a2 + a3);

    // (3) prefetch next step's x (one 8B load; consumed after next barrier)
    float n0 = 0.f, n1 = 0.f, n2 = 0.f, n3 = 0.f;
    if (t < 32 && step + 1 < SEQ) {
      ushort4 xv = *(const ushort4*)(proj + (long)ev[step + 1] * G4 + (q * 32 + t) * 4);
      n0 = f16u(xv.x); n1 = f16u(xv.y); n2 = f16u(xv.z); n3 = f16u(xv.w);
    }

    __syncthreads();                   // the only barrier per step

    // (4) finale on t<32: reduce 4x float4 from pl + activations + publish
    if (t < 32) {
      f32x4 p0 = *(const f32x4*)&pl[step & 1][t][0];
      f32x4 p1 = *(const f32x4*)&pl[step & 1][32 + t][0];
      f32x4 p2 = *(const f32x4*)&pl[step & 1][64 + t][0];
      f32x4 p3 = *(const f32x4*)&pl[step & 1][96 + t][0];
      float s0 = (p0[0] + p0[1]) + (p0[2] + p0[3]) + x0;
      float s1 = (p1[0] + p1[1]) + (p1[2] + p1[3]) + x1;
      float s2 = (p2[0] + p2[1]) + (p2[2] + p2[3]) + x2;
      float s3 = (p3[0] + p3[1]) + (p3[2] + p3[3]) + x3;
      float iv = sigm(s0), fv = sigm(s1), gv = tanh_(s2), ov = sigm(s3);
      c = fv * c + iv * gv;
      float hval = ov * tanh_(c);
      out[(step * BATCH + b) * HID + q * 32 + t] = hval;
      float hA = __shfl(hval, 2 * (t & 15));
      float hB = __shfl(hval, 2 * (t & 15) + 1);
      if (t < 16) {
        f16x2 pk; pk.x = (f16)hA; pk.y = (f16)hB;
        u64 val = (u64)__builtin_bit_cast(uint, pk) | ((u64)(uint)(step + 1) << 32);
        __hip_atomic_store(hb + (step & 1) * 128 + q * 16 + t, val,
                           __ATOMIC_RELAXED, __HIP_MEMORY_SCOPE_AGENT);
      }
    }
    x0 = n0; x1 = n1; x2 = n2; x3 = n3;
    // pl hazard: reads of pl[s&1] precede barrier(s+1); next write of pl[s&1] is
    // after barrier(s+1). Safe with one barrier.
  }
}

extern "C" void kernel_launch(void* const* d_in, const int* in_sizes, int n_in,
                              void* d_out, int out_size, void* d_ws, size_t ws_size,
                              hipStream_t stream) {
  (void)n_in; (void)out_size; (void)ws_size;
  const int* evs = (const int*)d_in[0];
  const int* anc = (const int*)d_in[1];
  const float* weight = (const float*)d_in[2];
  const float* emb = (const float*)d_in[3];
  const float* wih = (const float*)d_in[4];
  const float* whh = (const float*)d_in[5];
  const float* bih = (const float*)d_in[6];
  const float* bhh = (const float*)d_in[7];
  int D = in_sizes[1] / N_TYPES;

  char* ws = (char*)d_ws;
  f16* path = (f16*)(ws);                       // 10000*256*2 = 5,120,000 (dead after k_gemm)
  f16* wih_h = (f16*)(ws + 5242880);            // 524,288
  uint* whh_t = (uint*)(ws + 5767168);          // 524,288
  float* bias = (float*)(ws + 6291456);         // 4,096
  f16* proj = (f16*)(ws + 6295552);             // 10000*1024*2 = 20,480,000 (gate-packed)
  u64* hglob = (u64*)(ws + 26775552);           // 32*2*128*8 = 65,536
  float* out = (float*)d_out;

  k_conv<<<1024, 256, 0, stream>>>(wih, whh, bih, bhh, wih_h, whh_t, bias);
  k_path<<<N_TYPES, 256, 0, stream>>>(anc, weight, emb, D, path);
  k_gemm<<<dim3(79, 8), 256, 0, stream>>>(path, wih_h, bias, proj);
  hipMemsetAsync(hglob, 0, 32 * 2 * 128 * 8, stream);   // zero tags (replay-safe)
  k_lstm<<<256, 512, 0, stream>>>(evs, proj, whh_t, hglob, out);
}